// Round 1
// baseline (1277.889 us; speedup 1.0000x reference)
//
#include <hip/hip_runtime.h>
#include <hip/hip_bf16.h>
#include <stdint.h>

// LoRALinear fused: y = x @ (W + lora_A @ lora_B)^T + bias
// Strategy: fold LoRA into W_eff (cheap), split x and W_eff into bf16 hi+lo,
// run 3-segment bf16 MFMA GEMM (hi*hi + lo*hi + hi*lo) with fp32 accumulate.
// GEMM structure = m97 ladder step (128x128 tile, BK=32, global_load_lds w=16).

typedef unsigned short u16;
typedef __attribute__((ext_vector_type(8))) u16 u16x8;
typedef __attribute__((ext_vector_type(4))) u16 u16x4;
typedef __attribute__((ext_vector_type(8))) __bf16 bf16x8;
typedef __attribute__((ext_vector_type(4))) float f32x4;

#define IN_F 4096
#define OUT_F 4096
#define MTOT 8192  // B*S = 4*2048
#define RANK 16

__device__ __forceinline__ u16 f2bf(float f) {
  // round-to-nearest-even float -> bf16 (data has no NaN/inf)
  unsigned u = __float_as_uint(f);
  unsigned r = u + 0x7FFFu + ((u >> 16) & 1u);
  return (u16)(r >> 16);
}
__device__ __forceinline__ float bf2f(u16 h) {
  return __uint_as_float(((unsigned)h) << 16);
}

// ---------------- prep 1: split x into bf16 hi + lo ----------------
__global__ __launch_bounds__(256) void split_x_kernel(
    const float* __restrict__ x, u16* __restrict__ hi, u16* __restrict__ lo,
    int n4) {
  int idx = blockIdx.x * blockDim.x + threadIdx.x;
  const int stride = gridDim.x * blockDim.x;
  for (; idx < n4; idx += stride) {
    float4 v = ((const float4*)x)[idx];
    u16x4 h, l;
    h.x = f2bf(v.x); l.x = f2bf(v.x - bf2f(h.x));
    h.y = f2bf(v.y); l.y = f2bf(v.y - bf2f(h.y));
    h.z = f2bf(v.z); l.z = f2bf(v.z - bf2f(h.z));
    h.w = f2bf(v.w); l.w = f2bf(v.w - bf2f(h.w));
    ((u16x4*)hi)[idx] = h;
    ((u16x4*)lo)[idx] = l;
  }
}

// ------- prep 2: W_eff = W + lora_A @ lora_B, split into hi + lo -------
__global__ __launch_bounds__(256) void build_w_kernel(
    const float* __restrict__ W, const float* __restrict__ lA,
    const float* __restrict__ lB, u16* __restrict__ whi,
    u16* __restrict__ wlo) {
  const int o = blockIdx.x;  // one output-feature row per block
  float a[RANK];
#pragma unroll
  for (int r = 0; r < RANK; ++r) a[r] = lA[o * RANK + r];
  const float4* W4 = (const float4*)(W + (size_t)o * IN_F);
  u16x4* h4 = (u16x4*)(whi + (size_t)o * IN_F);
  u16x4* l4 = (u16x4*)(wlo + (size_t)o * IN_F);
  for (int i4 = threadIdx.x; i4 < IN_F / 4; i4 += blockDim.x) {
    float4 acc = W4[i4];
#pragma unroll
    for (int r = 0; r < RANK; ++r) {
      float4 b = ((const float4*)(lB + (size_t)r * IN_F))[i4];
      acc.x += a[r] * b.x; acc.y += a[r] * b.y;
      acc.z += a[r] * b.z; acc.w += a[r] * b.w;
    }
    u16x4 h, l;
    h.x = f2bf(acc.x); l.x = f2bf(acc.x - bf2f(h.x));
    h.y = f2bf(acc.y); l.y = f2bf(acc.y - bf2f(h.y));
    h.z = f2bf(acc.z); l.z = f2bf(acc.z - bf2f(h.z));
    h.w = f2bf(acc.w); l.w = f2bf(acc.w - bf2f(h.w));
    h4[i4] = h; l4[i4] = l;
  }
}

// ---------------- main: 3-segment bf16 GEMM, m97 structure ----------------
// C[m][n] = sum_seg sum_k A_seg[m][k] * B_seg[n][k]  (+ bias[n])
// 128x128 tile, BK=32, 4 waves (2x2), each wave 64x64 = 4x4 frags of 16x16.
#define GLD_LDS16(g, l)                                                  \
  __builtin_amdgcn_global_load_lds(                                      \
      (const __attribute__((address_space(1))) void*)(g),                \
      (__attribute__((address_space(3))) void*)(l), 16, 0, 0)

__global__ __launch_bounds__(256) void gemm_bf16x3_kernel(
    const u16* __restrict__ Xhi, const u16* __restrict__ Xlo,
    const u16* __restrict__ Whi, const u16* __restrict__ Wlo,
    const float* __restrict__ bias, float* __restrict__ out) {
  __shared__ __align__(16) u16 As[128 * 32];
  __shared__ __align__(16) u16 Bs[128 * 32];

  const int t = threadIdx.x;
  const int lane = t & 63;
  const int wv = t >> 6;        // wave 0..3
  const int wr = wv >> 1;       // wave row (2)
  const int wc = wv & 1;        // wave col (2)
  const int fr = lane & 15;     // fragment row/col index
  const int fq = lane >> 4;     // quarter 0..3

  // block -> tile: consecutive blocks share the B panel (n fixed, m streams)
  const int bm = blockIdx.x & 63;   // M/128 = 64
  const int bn = blockIdx.x >> 6;   // N/128 = 32
  const int m0 = bm * 128;
  const int n0 = bn * 128;

  // staging: 256 thr * 16B = 4KiB/issue; tile 8KiB -> 2 issues each for A,B
  const int srow = t >> 2;           // 0..63
  const int scol = (t & 3) * 8;      // 0,8,16,24
  const size_t a_off0 = (size_t)(m0 + srow) * IN_F + scol;
  const size_t a_off1 = a_off0 + (size_t)64 * IN_F;
  const size_t b_off0 = (size_t)(n0 + srow) * IN_F + scol;
  const size_t b_off1 = b_off0 + (size_t)64 * IN_F;
  u16* a_dst0 = As + t * 8;
  u16* a_dst1 = As + 2048 + t * 8;
  u16* b_dst0 = Bs + t * 8;
  u16* b_dst1 = Bs + 2048 + t * 8;

  f32x4 acc[4][4];
#pragma unroll
  for (int i = 0; i < 4; ++i)
#pragma unroll
    for (int j = 0; j < 4; ++j) {
      acc[i][j][0] = 0.f; acc[i][j][1] = 0.f;
      acc[i][j][2] = 0.f; acc[i][j][3] = 0.f;
    }

  const u16* Aseg[3] = {Xhi, Xlo, Xhi};
  const u16* Bseg[3] = {Whi, Whi, Wlo};

#pragma unroll 1
  for (int seg = 0; seg < 3; ++seg) {
    const u16* __restrict__ Ag = Aseg[seg];
    const u16* __restrict__ Bg = Bseg[seg];
#pragma unroll 1
    for (int kt = 0; kt < IN_F / 32; ++kt) {
      const int k0 = kt * 32;
      __syncthreads();  // previous iter's ds_reads done before overwrite
      GLD_LDS16(Ag + a_off0 + k0, a_dst0);
      GLD_LDS16(Ag + a_off1 + k0, a_dst1);
      GLD_LDS16(Bg + b_off0 + k0, b_dst0);
      GLD_LDS16(Bg + b_off1 + k0, b_dst1);
      __syncthreads();  // compiler drains vmcnt(0) before barrier

      u16x8 av[4], bv[4];
#pragma unroll
      for (int mi = 0; mi < 4; ++mi)
        av[mi] = *(const u16x8*)&As[(wr * 64 + mi * 16 + fr) * 32 + fq * 8];
#pragma unroll
      for (int ni = 0; ni < 4; ++ni)
        bv[ni] = *(const u16x8*)&Bs[(wc * 64 + ni * 16 + fr) * 32 + fq * 8];

#pragma unroll
      for (int mi = 0; mi < 4; ++mi)
#pragma unroll
        for (int ni = 0; ni < 4; ++ni)
          acc[mi][ni] = __builtin_amdgcn_mfma_f32_16x16x32_bf16(
              __builtin_bit_cast(bf16x8, av[mi]),
              __builtin_bit_cast(bf16x8, bv[ni]), acc[mi][ni], 0, 0, 0);
    }
  }

  // epilogue: C/D layout col=lane&15, row=(lane>>4)*4+reg (m89/m91 verified)
  const int rowbase = m0 + wr * 64;
  const int colbase = n0 + wc * 64;
#pragma unroll
  for (int mi = 0; mi < 4; ++mi)
#pragma unroll
    for (int ni = 0; ni < 4; ++ni) {
      const int col = colbase + ni * 16 + fr;
      const float bb = bias[col];
#pragma unroll
      for (int r = 0; r < 4; ++r) {
        const int row = rowbase + mi * 16 + fq * 4 + r;
        out[(size_t)row * OUT_F + col] = acc[mi][ni][r] + bb;
      }
    }
}

// -------- fallback (only if ws too small): fp32 vector GEMM, LoRA fused --------
__global__ __launch_bounds__(256) void gemm_f32_fallback(
    const float* __restrict__ X, const float* __restrict__ W,
    const float* __restrict__ lA, const float* __restrict__ lB,
    const float* __restrict__ bias, float* __restrict__ out) {
  __shared__ __align__(16) float Xs[64 * 32];
  __shared__ __align__(16) float Ws[64 * 32];
  const int t = threadIdx.x;
  const int bm = blockIdx.x & 127;  // M/64 = 128
  const int bn = blockIdx.x >> 7;   // N/64 = 64
  const int m0 = bm * 64, n0 = bn * 64;
  const int tx = t & 15, ty = t >> 4;
  float acc[4][4] = {};
  for (int k0 = 0; k0 < IN_F; k0 += 32) {
    __syncthreads();
#pragma unroll
    for (int q = 0; q < 2; ++q) {
      const int e4 = t * 2 + q;
      const int row = e4 >> 3;
      const int col = (e4 & 7) * 4;
      float4 xv = *(const float4*)(X + (size_t)(m0 + row) * IN_F + k0 + col);
      *(float4*)(Xs + row * 32 + col) = xv;
      float4 wv = *(const float4*)(W + (size_t)(n0 + row) * IN_F + k0 + col);
#pragma unroll
      for (int r = 0; r < RANK; ++r) {
        const float a = lA[(n0 + row) * RANK + r];
        const float4 b = *(const float4*)(lB + (size_t)r * IN_F + k0 + col);
        wv.x += a * b.x; wv.y += a * b.y; wv.z += a * b.z; wv.w += a * b.w;
      }
      *(float4*)(Ws + row * 32 + col) = wv;
    }
    __syncthreads();
#pragma unroll
    for (int kk = 0; kk < 32; ++kk) {
      float xr[4], wcol[4];
#pragma unroll
      for (int i = 0; i < 4; ++i) xr[i] = Xs[(ty * 4 + i) * 32 + kk];
#pragma unroll
      for (int j = 0; j < 4; ++j) wcol[j] = Ws[(tx * 4 + j) * 32 + kk];
#pragma unroll
      for (int i = 0; i < 4; ++i)
#pragma unroll
        for (int j = 0; j < 4; ++j) acc[i][j] += xr[i] * wcol[j];
    }
  }
#pragma unroll
  for (int i = 0; i < 4; ++i) {
    const int row = m0 + ty * 4 + i;
#pragma unroll
    for (int j = 0; j < 4; ++j) {
      const int col = n0 + tx * 4 + j;
      out[(size_t)row * OUT_F + col] = acc[i][j] + bias[col];
    }
  }
}

extern "C" void kernel_launch(void* const* d_in, const int* in_sizes, int n_in,
                              void* d_out, int out_size, void* d_ws,
                              size_t ws_size, hipStream_t stream) {
  const float* x    = (const float*)d_in[0];
  const float* W    = (const float*)d_in[1];
  const float* bias = (const float*)d_in[2];
  const float* lA   = (const float*)d_in[3];
  const float* lB   = (const float*)d_in[4];
  float* out = (float*)d_out;

  const size_t MK = (size_t)MTOT * IN_F;   // 33.5M elems
  const size_t NK = (size_t)OUT_F * IN_F;  // 16.7M elems
  const size_t need = (MK * 2 + NK * 2) * sizeof(u16);  // 192 MiB

  if (ws_size >= need) {
    u16* Xhi = (u16*)d_ws;
    u16* Xlo = Xhi + MK;
    u16* Whi = Xlo + MK;
    u16* Wlo = Whi + NK;
    split_x_kernel<<<2048, 256, 0, stream>>>(x, Xhi, Xlo, (int)(MK / 4));
    build_w_kernel<<<OUT_F, 256, 0, stream>>>(W, lA, lB, Whi, Wlo);
    gemm_bf16x3_kernel<<<64 * 32, 256, 0, stream>>>(Xhi, Xlo, Whi, Wlo, bias,
                                                    out);
  } else {
    gemm_f32_fallback<<<128 * 64, 256, 0, stream>>>(x, W, lA, lB, bias, out);
  }
}

// Round 3
// 980.077 us; speedup vs baseline: 1.3039x; 1.3039x over previous
//
#include <hip/hip_runtime.h>
#include <hip/hip_bf16.h>
#include <stdint.h>

// LoRALinear fused: y = x @ (W + lora_A @ lora_B)^T + bias
// W_eff = W + A@B folded on device; x and W_eff split into bf16 hi+lo;
// 3-segment bf16 MFMA GEMM (hi*hi + lo*hi + hi*lo), fp32 accumulate.
// GEMM = deep-pipelined counted-vmcnt schedule (T1+T2+T3+T4+T5):
//   256x256 tile, BK=32, 4-buffer LDS ring (128 KiB), 8 waves (2Mx4N),
//   prefetch depth 3 K-tiles, s_waitcnt vmcnt(8) per tile (never 0),
//   XOR-swizzled LDS (octet-conflict-free ds_read_b128), setprio on MFMA.

typedef unsigned short u16;
typedef __attribute__((ext_vector_type(8))) u16 u16x8;
typedef __attribute__((ext_vector_type(4))) u16 u16x4;
typedef __attribute__((ext_vector_type(8))) __bf16 bf16x8;
typedef __attribute__((ext_vector_type(4))) float f32x4;

#define IN_F 4096
#define OUT_F 4096
#define MTOT 8192  // B*S
#define RANK 16
#define NTILE 384  // 3 segments * (4096/32) K-tiles

__device__ __forceinline__ u16 f2bf(float f) {
  unsigned u = __float_as_uint(f);
  unsigned r = u + 0x7FFFu + ((u >> 16) & 1u);
  return (u16)(r >> 16);
}
__device__ __forceinline__ float bf2f(u16 h) {
  return __uint_as_float(((unsigned)h) << 16);
}

// ---------------- prep 1: split x into bf16 hi + lo ----------------
__global__ __launch_bounds__(256) void split_x_kernel(
    const float* __restrict__ x, u16* __restrict__ hi, u16* __restrict__ lo,
    int n4) {
  int idx = blockIdx.x * blockDim.x + threadIdx.x;
  const int stride = gridDim.x * blockDim.x;
  for (; idx < n4; idx += stride) {
    float4 v = ((const float4*)x)[idx];
    u16x4 h, l;
    h.x = f2bf(v.x); l.x = f2bf(v.x - bf2f(h.x));
    h.y = f2bf(v.y); l.y = f2bf(v.y - bf2f(h.y));
    h.z = f2bf(v.z); l.z = f2bf(v.z - bf2f(h.z));
    h.w = f2bf(v.w); l.w = f2bf(v.w - bf2f(h.w));
    ((u16x4*)hi)[idx] = h;
    ((u16x4*)lo)[idx] = l;
  }
}

// ------- prep 2: W_eff = W + lora_A @ lora_B, split into hi + lo -------
// 2 output rows per block (128 thr each) to shorten the dispatch tail.
__global__ __launch_bounds__(256) void build_w_kernel(
    const float* __restrict__ W, const float* __restrict__ lA,
    const float* __restrict__ lB, u16* __restrict__ whi,
    u16* __restrict__ wlo) {
  const int o = blockIdx.x * 2 + (threadIdx.x >> 7);
  const int tl = threadIdx.x & 127;
  float a[RANK];
#pragma unroll
  for (int r = 0; r < RANK; ++r) a[r] = lA[o * RANK + r];
  const float4* W4 = (const float4*)(W + (size_t)o * IN_F);
  u16x4* h4 = (u16x4*)(whi + (size_t)o * IN_F);
  u16x4* l4 = (u16x4*)(wlo + (size_t)o * IN_F);
  for (int i4 = tl; i4 < IN_F / 4; i4 += 128) {
    float4 acc = W4[i4];
#pragma unroll
    for (int r = 0; r < RANK; ++r) {
      float4 b = ((const float4*)(lB + (size_t)r * IN_F))[i4];
      acc.x += a[r] * b.x; acc.y += a[r] * b.y;
      acc.z += a[r] * b.z; acc.w += a[r] * b.w;
    }
    u16x4 h, l;
    h.x = f2bf(acc.x); l.x = f2bf(acc.x - bf2f(h.x));
    h.y = f2bf(acc.y); l.y = f2bf(acc.y - bf2f(h.y));
    h.z = f2bf(acc.z); l.z = f2bf(acc.z - bf2f(h.z));
    h.w = f2bf(acc.w); l.w = f2bf(acc.w - bf2f(h.w));
    h4[i4] = h; l4[i4] = l;
  }
}

// ---------------- main: deep-pipelined 3-segment bf16 GEMM ----------------
#define GLD_LDS16(g, l)                                                  \
  __builtin_amdgcn_global_load_lds(                                      \
      (const __attribute__((address_space(1))) void*)(g),                \
      (__attribute__((address_space(3))) void*)(l), 16, 0, 0)

__global__ __launch_bounds__(512, 2) void gemm_pipe_kernel(
    const u16* __restrict__ Xhi, const u16* __restrict__ Xlo,
    const u16* __restrict__ Whi, const u16* __restrict__ Wlo,
    const float* __restrict__ bias, float* __restrict__ out) {
  // 4 ring buffers x (A 256x32 | B 256x32) u16 = 4 x 32 KiB = 128 KiB
  __shared__ __align__(16) u16 LDS[4 * 16384];

  const int t = threadIdx.x;
  const int lane = t & 63;
  const int wv = t >> 6;   // 0..7
  const int wm = wv >> 2;  // 0..1  (wave's 128-row half of the 256-row tile)
  const int wn = wv & 3;   // 0..3  (wave's 64-col strip of the 256-col tile)
  const int fr = lane & 15;
  const int fq = lane >> 4;

  // T1: XCD-aware swizzle. 512 wgs, 64 contiguous per XCD (512 % 8 == 0).
  const int wg = ((blockIdx.x & 7) << 6) | (blockIdx.x >> 3);
  const int m0 = (wg >> 4) * 256;  // 32 m-tiles
  const int n0 = (wg & 15) * 256;  // 16 n-tiles

  // ---- staging geometry (per-thread, tile-invariant) ----
  // LDS is lane-linear (global_load_lds constraint); the XOR swizzle is
  // applied on the GLOBAL source column so the swizzled READ below sees
  // global chunk k of row r at lds[r*4 + (k ^ ((r>>1)&3))] (rule #21).
  const int srow = t >> 2;                          // 0..127 per round
  const int scol = ((t & 3) ^ ((t >> 3) & 3)) * 8;  // pre-swizzled source col
  const size_t a_off0 = (size_t)(m0 + srow) * IN_F + scol;
  const size_t a_off1 = (size_t)(m0 + 128 + srow) * IN_F + scol;
  const size_t b_off0 = (size_t)(n0 + srow) * IN_F + scol;
  const size_t b_off1 = (size_t)(n0 + 128 + srow) * IN_F + scol;
  const int sdst0 = t * 8;         // u16 units, round 0
  const int sdst1 = 4096 + t * 8;  // round 1

  // ---- fragment read offsets (u16 units, swizzled) ----
  // unit = row*4 + (k ^ ((row>>1)&3)); row stride 64B. Per consecutive
  // lane-octet the 8 ds_read_b128 spans hit all 8 bank-groups once.
  const int swz = (fq ^ ((fr >> 1) & 3)) * 8;
  const int a_rd = (wm * 128 + fr) * 32 + swz;
  const int b_rd = (wn * 64 + fr) * 32 + swz;

  f32x4 acc[8][4];
#pragma unroll
  for (int i = 0; i < 8; ++i)
#pragma unroll
    for (int j = 0; j < 4; ++j) {
      acc[i][j][0] = 0.f; acc[i][j][1] = 0.f;
      acc[i][j][2] = 0.f; acc[i][j][3] = 0.f;
    }

  // segment g>>7: A sources {Xhi, Xlo, Xhi}; B sources {Whi, Whi, Wlo}
  auto stageA = [&](int g, int buf) {
    const int sg = g >> 7;
    const u16* ap = (sg == 1) ? Xlo : Xhi;
    const int k0 = (g & 127) << 5;
    u16* dst = (u16*)&LDS[buf * 16384];
    GLD_LDS16(ap + a_off0 + k0, dst + sdst0);
    GLD_LDS16(ap + a_off1 + k0, dst + sdst1);
  };
  auto stageB = [&](int g, int buf) {
    const int sg = g >> 7;
    const u16* bp = (sg == 2) ? Wlo : Whi;
    const int k0 = (g & 127) << 5;
    u16* dst = (u16*)&LDS[buf * 16384 + 8192];
    GLD_LDS16(bp + b_off0 + k0, dst + sdst0);
    GLD_LDS16(bp + b_off1 + k0, dst + sdst1);
  };

  // prologue: stage tiles 0,1,2 (12 loads; per-wave queue order A,B per tile)
  stageA(0, 0); stageB(0, 0);
  stageA(1, 1); stageB(1, 1);
  stageA(2, 2); stageB(2, 2);

#pragma unroll 1
  for (int tt = 0; tt < NTILE; ++tt) {
    const int buf = tt & 3;
    const u16* Ab = &LDS[buf * 16384];
    const u16* Bb = Ab + 8192;
    int g = tt + 3;
    if (g >= NTILE) g = NTILE - 1;  // clamped dummy stage: uniform vmcnt count
    const int pbuf = (tt + 3) & 3;  // == (tt-1)&3, retired at this barrier

    // per-wave: own tile-tt loads landed (8 newer = tiles tt+1,tt+2 in flight)
    asm volatile("s_waitcnt vmcnt(8)" ::: "memory");
    __builtin_amdgcn_s_barrier();  // all waves past their wait -> tile ready
    __builtin_amdgcn_sched_barrier(0);

    // ---- phase 0: mi 0..3 x ni 0..3 ----
    u16x8 af[4], bf[4];
#pragma unroll
    for (int mi = 0; mi < 4; ++mi)
      af[mi] = *(const u16x8*)&Ab[a_rd + mi * 512];
#pragma unroll
    for (int ni = 0; ni < 4; ++ni)
      bf[ni] = *(const u16x8*)&Bb[b_rd + ni * 512];
    stageA(g, pbuf);  // safe: pbuf's last readers drained before the barrier
    asm volatile("s_waitcnt lgkmcnt(0)" ::: "memory");
    __builtin_amdgcn_sched_barrier(0);  // rule #18: pin MFMA below the wait
    __builtin_amdgcn_s_setprio(1);
#pragma unroll
    for (int mi = 0; mi < 4; ++mi)
#pragma unroll
      for (int ni = 0; ni < 4; ++ni)
        acc[mi][ni] = __builtin_amdgcn_mfma_f32_16x16x32_bf16(
            __builtin_bit_cast(bf16x8, af[mi]),
            __builtin_bit_cast(bf16x8, bf[ni]), acc[mi][ni], 0, 0, 0);
    __builtin_amdgcn_s_setprio(0);
    __builtin_amdgcn_s_barrier();  // phase lockstep

    // ---- phase 1: mi 4..7 x ni 0..3 (bf reused) ----
#pragma unroll
    for (int mi = 0; mi < 4; ++mi)
      af[mi] = *(const u16x8*)&Ab[a_rd + 2048 + mi * 512];
    stageB(g, pbuf);
    asm volatile("s_waitcnt lgkmcnt(0)" ::: "memory");
    __builtin_amdgcn_sched_barrier(0);
    __builtin_amdgcn_s_setprio(1);
#pragma unroll
    for (int mi = 0; mi < 4; ++mi)
#pragma unroll
      for (int ni = 0; ni < 4; ++ni)
        acc[4 + mi][ni] = __builtin_amdgcn_mfma_f32_16x16x32_bf16(
            __builtin_bit_cast(bf16x8, af[mi]),
            __builtin_bit_cast(bf16x8, bf[ni]), acc[4 + mi][ni], 0, 0, 0);
    __builtin_amdgcn_s_setprio(0);
    // no closing barrier: next tile's vmcnt+barrier closes this tile
  }

  // epilogue: C/D layout col=lane&15, row=(lane>>4)*4+reg (m89/m91 verified)
#pragma unroll
  for (int mig = 0; mig < 8; ++mig) {
    const int row = m0 + wm * 128 + mig * 16 + fq * 4;
#pragma unroll
    for (int ni = 0; ni < 4; ++ni) {
      const int col = n0 + wn * 64 + ni * 16 + fr;
      const float bb = bias[col];
#pragma unroll
      for (int r = 0; r < 4; ++r)
        out[(size_t)(row + r) * OUT_F + col] = acc[mig][ni][r] + bb;
    }
  }
}

// -------- fallback (only if ws too small): fp32 vector GEMM, LoRA fused --------
__global__ __launch_bounds__(256) void gemm_f32_fallback(
    const float* __restrict__ X, const float* __restrict__ W,
    const float* __restrict__ lA, const float* __restrict__ lB,
    const float* __restrict__ bias, float* __restrict__ out) {
  __shared__ __align__(16) float Xs[64 * 32];
  __shared__ __align__(16) float Ws[64 * 32];
  const int t = threadIdx.x;
  const int bm = blockIdx.x & 127;
  const int bn = blockIdx.x >> 7;
  const int m0 = bm * 64, n0 = bn * 64;
  const int tx = t & 15, ty = t >> 4;
  float acc[4][4] = {};
  for (int k0 = 0; k0 < IN_F; k0 += 32) {
    __syncthreads();
#pragma unroll
    for (int q = 0; q < 2; ++q) {
      const int e4 = t * 2 + q;
      const int row = e4 >> 3;
      const int col = (e4 & 7) * 4;
      float4 xv = *(const float4*)(X + (size_t)(m0 + row) * IN_F + k0 + col);
      *(float4*)(Xs + row * 32 + col) = xv;
      float4 wv = *(const float4*)(W + (size_t)(n0 + row) * IN_F + k0 + col);
#pragma unroll
      for (int r = 0; r < RANK; ++r) {
        const float a = lA[(n0 + row) * RANK + r];
        const float4 b = *(const float4*)(lB + (size_t)r * IN_F + k0 + col);
        wv.x += a * b.x; wv.y += a * b.y; wv.z += a * b.z; wv.w += a * b.w;
      }
      *(float4*)(Ws + row * 32 + col) = wv;
    }
    __syncthreads();
#pragma unroll
    for (int kk = 0; kk < 32; ++kk) {
      float xr[4], wcol[4];
#pragma unroll
      for (int i = 0; i < 4; ++i) xr[i] = Xs[(ty * 4 + i) * 32 + kk];
#pragma unroll
      for (int j = 0; j < 4; ++j) wcol[j] = Ws[(tx * 4 + j) * 32 + kk];
#pragma unroll
      for (int i = 0; i < 4; ++i)
#pragma unroll
        for (int j = 0; j < 4; ++j) acc[i][j] += xr[i] * wcol[j];
    }
  }
#pragma unroll
  for (int i = 0; i < 4; ++i) {
    const int row = m0 + ty * 4 + i;
#pragma unroll
    for (int j = 0; j < 4; ++j) {
      const int col = n0 + tx * 4 + j;
      out[(size_t)row * OUT_F + col] = acc[i][j] + bias[col];
    }
  }
}

extern "C" void kernel_launch(void* const* d_in, const int* in_sizes, int n_in,
                              void* d_out, int out_size, void* d_ws,
                              size_t ws_size, hipStream_t stream) {
  const float* x    = (const float*)d_in[0];
  const float* W    = (const float*)d_in[1];
  const float* bias = (const float*)d_in[2];
  const float* lA   = (const float*)d_in[3];
  const float* lB   = (const float*)d_in[4];
  float* out = (float*)d_out;

  const size_t MK = (size_t)MTOT * IN_F;
  const size_t NK = (size_t)OUT_F * IN_F;
  const size_t need = (MK * 2 + NK * 2) * sizeof(u16);  // 192 MiB

  if (ws_size >= need) {
    u16* Xhi = (u16*)d_ws;
    u16* Xlo = Xhi + MK;
    u16* Whi = Xlo + MK;
    u16* Wlo = Whi + NK;
    split_x_kernel<<<4096, 256, 0, stream>>>(x, Xhi, Xlo, (int)(MK / 4));
    build_w_kernel<<<OUT_F / 2, 256, 0, stream>>>(W, lA, lB, Whi, Wlo);
    gemm_pipe_kernel<<<512, 512, 0, stream>>>(Xhi, Xlo, Whi, Wlo, bias, out);
  } else {
    gemm_f32_fallback<<<128 * 64, 256, 0, stream>>>(x, W, lA, lB, bias, out);
  }
}

// Round 6
// 910.638 us; speedup vs baseline: 1.4033x; 1.0763x over previous
//
#include <hip/hip_runtime.h>
#include <hip/hip_bf16.h>
#include <stdint.h>

// LoRALinear fused: y = x @ (W + lora_A @ lora_B)^T + bias
// W_eff = W + A@B folded; x, W_eff split to bf16 hi+lo; 3-segment bf16 MFMA
// GEMM (hi*hi + lo*hi + hi*lo), fp32 accumulate. K_eff = 3*4096 = 12288.
// R5/R6 GEMM: BM=BN=256, BK=64, double-buffered LDS (128 KiB), 8 waves (2Mx4N),
// ONE barrier + ONE vmcnt wait per 64-K tile, 4 quadrant phases with held
// fragments (24 ds_read_b128/tile/wave, the minimum), NO intra-tile barriers
// so the 2 waves/SIMD anti-phase (MFMA of one covers ds_read of the other).
// XOR swizzle chunk^=(row&7): conflict-free ds_read_b128 (class verified R3).

typedef unsigned short u16;
typedef __attribute__((ext_vector_type(8))) u16 u16x8;
typedef __attribute__((ext_vector_type(4))) u16 u16x4;
typedef __attribute__((ext_vector_type(8))) __bf16 bf16x8;
typedef __attribute__((ext_vector_type(4))) float f32x4;

#define IN_F 4096
#define OUT_F 4096
#define MTOT 8192  // B*S
#define RANK 16
#define NT64 192  // 3 segments * (4096/64) K-tiles

__device__ __forceinline__ u16 f2bf(float f) {
  unsigned u = __float_as_uint(f);
  unsigned r = u + 0x7FFFu + ((u >> 16) & 1u);
  return (u16)(r >> 16);
}
__device__ __forceinline__ float bf2f(u16 h) {
  return __uint_as_float(((unsigned)h) << 16);
}

// ---------------- fused prep: split x | build+split W_eff ----------------
// blocks [0,2048): x -> Xhi,Xlo.  blocks [2048,4096): W_eff rows -> Whi,Wlo.
__global__ __launch_bounds__(256) void prep_kernel(
    const float* __restrict__ x, const float* __restrict__ W,
    const float* __restrict__ lA, const float* __restrict__ lB,
    u16* __restrict__ xhi, u16* __restrict__ xlo, u16* __restrict__ whi,
    u16* __restrict__ wlo) {
  if (blockIdx.x < 2048) {
    const int n4 = (MTOT * IN_F) / 4;
    int idx = blockIdx.x * 256 + threadIdx.x;
    for (; idx < n4; idx += 2048 * 256) {
      float4 v = ((const float4*)x)[idx];
      u16x4 h, l;
      h.x = f2bf(v.x); l.x = f2bf(v.x - bf2f(h.x));
      h.y = f2bf(v.y); l.y = f2bf(v.y - bf2f(h.y));
      h.z = f2bf(v.z); l.z = f2bf(v.z - bf2f(h.z));
      h.w = f2bf(v.w); l.w = f2bf(v.w - bf2f(h.w));
      ((u16x4*)xhi)[idx] = h;
      ((u16x4*)xlo)[idx] = l;
    }
  } else {
    const int o = (blockIdx.x - 2048) * 2 + (threadIdx.x >> 7);
    const int tl = threadIdx.x & 127;
    float a[RANK];
#pragma unroll
    for (int r = 0; r < RANK; ++r) a[r] = lA[o * RANK + r];
    const float4* W4 = (const float4*)(W + (size_t)o * IN_F);
    u16x4* h4 = (u16x4*)(whi + (size_t)o * IN_F);
    u16x4* l4 = (u16x4*)(wlo + (size_t)o * IN_F);
    for (int i4 = tl; i4 < IN_F / 4; i4 += 128) {
      float4 acc = W4[i4];
#pragma unroll
      for (int r = 0; r < RANK; ++r) {
        float4 b = ((const float4*)(lB + (size_t)r * IN_F))[i4];
        acc.x += a[r] * b.x; acc.y += a[r] * b.y;
        acc.z += a[r] * b.z; acc.w += a[r] * b.w;
      }
      u16x4 h, l;
      h.x = f2bf(acc.x); l.x = f2bf(acc.x - bf2f(h.x));
      h.y = f2bf(acc.y); l.y = f2bf(acc.y - bf2f(h.y));
      h.z = f2bf(acc.z); l.z = f2bf(acc.z - bf2f(h.z));
      h.w = f2bf(acc.w); l.w = f2bf(acc.w - bf2f(h.w));
      h4[i4] = h; l4[i4] = l;
    }
  }
}

// ---------------- main: BK=64 quadrant-phase 3-segment bf16 GEMM -----------
#define GLD_LDS16(g, l)                                                  \
  __builtin_amdgcn_global_load_lds(                                      \
      (const __attribute__((address_space(1))) void*)(g),                \
      (__attribute__((address_space(3))) void*)(l), 16, 0, 0)

__global__ __launch_bounds__(512, 2) void gemm_pipe_kernel(
    const u16* __restrict__ Xhi, const u16* __restrict__ Xlo,
    const u16* __restrict__ Whi, const u16* __restrict__ Wlo,
    const float* __restrict__ bias, float* __restrict__ out) {
  // 2 bufs x (A 256x64 | B 256x64) bf16 = 2 x 64 KiB = 128 KiB.
  // unit = 16B chunk. Row r (0..255) slot s (0..7): unit = r*8+s.
  // Swizzle: global chunk c of row r lands at slot s = c ^ (r&7).
  __shared__ __align__(16) u16 LDS[65536];

  const int t = threadIdx.x;
  const int lane = t & 63;
  const int wv = t >> 6;   // 0..7
  const int wm = wv >> 2;  // 0..1: 128-row half
  const int wn = wv & 3;   // 0..3: 64-col strip
  const int fr = lane & 15;
  const int fq = lane >> 4;

  // T1: XCD swizzle (bijective: 512 % 8 == 0), 64 contiguous wgs per XCD.
  const int wg = ((blockIdx.x & 7) << 6) | (blockIdx.x >> 3);
  const int m0 = (wg >> 4) * 256;  // 32 m-tiles
  const int n0 = (wg & 15) * 256;  // 16 n-tiles

  // staging source (element offsets): thread t stages dst unit (h*1024+q*512+t)
  // <- global row (h&1)*128 + q*64 + (t>>3), chunk (t&7)^((t>>3)&7).
  const int scol = ((t & 7) ^ ((t >> 3) & 7)) * 8;
  const size_t aoff = (size_t)(m0 + (t >> 3)) * IN_F + scol;
  const size_t boff = (size_t)(n0 + (t >> 3)) * IN_F + scol;

  // ds_read lane offsets (u16): frag(row base R, kstep ks) at
  // (R+fr)*64 + ((ks*4+fq)^(fr&7))*8  = R*64 + lk[ks]   (R%8==0 everywhere)
  const int lk0 = fr * 64 + (((0 * 4 + fq) ^ (fr & 7)) * 8);
  const int lk1 = fr * 64 + (((1 * 4 + fq) ^ (fr & 7)) * 8);

  f32x4 acc[8][4];  // [mh*4+mi][nh*2+ci]
#pragma unroll
  for (int i = 0; i < 8; ++i)
#pragma unroll
    for (int j = 0; j < 4; ++j) {
      acc[i][j][0] = 0.f; acc[i][j][1] = 0.f;
      acc[i][j][2] = 0.f; acc[i][j][3] = 0.f;
    }

  // segment g>>6: A from {Xhi,Xlo,Xhi}; B from {Whi,Whi,Wlo}
  auto stageA = [&](int g, int sbuf) {  // A halves h0,h1 (4 gld)
    const int sg = g >> 6;
    const u16* ap = (sg == 1) ? Xlo : Xhi;
    const int k0 = (g & 63) << 6;
    u16* dA = (u16*)&LDS[sbuf * 32768];
    const u16* s = ap + aoff + k0;
    GLD_LDS16(s, dA + t * 8);                                // h0 q0
    GLD_LDS16(s + (size_t)64 * IN_F, dA + (512 + t) * 8);    // h0 q1
    GLD_LDS16(s + (size_t)128 * IN_F, dA + (1024 + t) * 8);  // h1 q0
    GLD_LDS16(s + (size_t)192 * IN_F, dA + (1536 + t) * 8);  // h1 q1
  };
  auto stageB0 = [&](int g, int sbuf) {  // B rows 0..127 (2 gld)
    const int sg = g >> 6;
    const u16* bp = (sg == 2) ? Wlo : Whi;
    const int k0 = (g & 63) << 6;
    u16* dB = (u16*)&LDS[sbuf * 32768 + 16384];
    const u16* s = bp + boff + k0;
    GLD_LDS16(s, dB + t * 8);
    GLD_LDS16(s + (size_t)64 * IN_F, dB + (512 + t) * 8);
  };
  auto stageB1 = [&](int g, int sbuf) {  // B rows 128..255 (2 gld)
    const int sg = g >> 6;
    const u16* bp = (sg == 2) ? Wlo : Whi;
    const int k0 = (g & 63) << 6;
    u16* dB = (u16*)&LDS[sbuf * 32768 + 16384];
    const u16* s = bp + boff + k0;
    GLD_LDS16(s + (size_t)128 * IN_F, dB + (1024 + t) * 8);
    GLD_LDS16(s + (size_t)192 * IN_F, dB + (1536 + t) * 8);
  };

#define MFMA_Q(AIDX, BARR, BIDX, ACC)                                   \
  ACC = __builtin_amdgcn_mfma_f32_16x16x32_bf16(                        \
      __builtin_bit_cast(bf16x8, af[AIDX]),                             \
      __builtin_bit_cast(bf16x8, BARR[BIDX]), ACC, 0, 0, 0)

  // prologue: stage tile 0 into buf 0 (8 loads)
  stageA(0, 0); stageB0(0, 0); stageB1(0, 0);

#pragma unroll 1
  for (int tt = 0; tt < NT64; ++tt) {
    const int buf = tt & 1;
    const u16* Ab = &LDS[buf * 32768];
    const u16* Bb = Ab + 16384;
    int g = tt + 1;
    if (g >= NT64) g = NT64 - 1;  // dummy re-stage: uniform vmcnt ledger
    const int sbuf = buf ^ 1;

    // drain tile-tt's 8 loads (issued >=1.5 phases ago: near-zero stall);
    // barrier => ALL waves' tile-tt loads landed AND all buf readers of the
    // previous use are done (each wave lgkmcnt(0)-drained before arriving).
    asm volatile("s_waitcnt vmcnt(0)" ::: "memory");
    __builtin_amdgcn_s_barrier();
    // rule #18-class fence: raw s_barrier is not a compiler memory fence --
    // without this, hipcc may hoist the ds_reads below above the barrier,
    // racing other waves' still-in-flight global_load_lds writes.
    __builtin_amdgcn_sched_barrier(0);

    u16x8 af[8], bf0[4], bf1[4];

    // ---- P0 (mh0,nh0): read af(mh0) 8 + bf0 4; stage A(t+1) ----
#pragma unroll
    for (int mi = 0; mi < 4; ++mi) {
      af[mi * 2 + 0] = *(const u16x8*)&Ab[wm * 8192 + mi * 1024 + lk0];
      af[mi * 2 + 1] = *(const u16x8*)&Ab[wm * 8192 + mi * 1024 + lk1];
    }
#pragma unroll
    for (int ci = 0; ci < 2; ++ci) {
      bf0[ci * 2 + 0] = *(const u16x8*)&Bb[wn * 4096 + ci * 1024 + lk0];
      bf0[ci * 2 + 1] = *(const u16x8*)&Bb[wn * 4096 + ci * 1024 + lk1];
    }
    stageA(g, sbuf);
    asm volatile("s_waitcnt lgkmcnt(0)" ::: "memory");
    __builtin_amdgcn_sched_barrier(0);
    __builtin_amdgcn_s_setprio(1);
#pragma unroll
    for (int mi = 0; mi < 4; ++mi)
#pragma unroll
      for (int ci = 0; ci < 2; ++ci) {
        MFMA_Q(mi * 2 + 0, bf0, ci * 2 + 0, acc[mi][ci]);
        MFMA_Q(mi * 2 + 1, bf0, ci * 2 + 1, acc[mi][ci]);
      }
    __builtin_amdgcn_s_setprio(0);

    // ---- P1 (mh0,nh1): read bf1 4; stage B0(t+1) ----
#pragma unroll
    for (int ci = 0; ci < 2; ++ci) {
      bf1[ci * 2 + 0] = *(const u16x8*)&Bb[wn * 4096 + 2048 + ci * 1024 + lk0];
      bf1[ci * 2 + 1] = *(const u16x8*)&Bb[wn * 4096 + 2048 + ci * 1024 + lk1];
    }
    stageB0(g, sbuf);
    asm volatile("s_waitcnt lgkmcnt(0)" ::: "memory");
    __builtin_amdgcn_sched_barrier(0);
    __builtin_amdgcn_s_setprio(1);
#pragma unroll
    for (int mi = 0; mi < 4; ++mi)
#pragma unroll
      for (int ci = 0; ci < 2; ++ci) {
        MFMA_Q(mi * 2 + 0, bf1, ci * 2 + 0, acc[mi][2 + ci]);
        MFMA_Q(mi * 2 + 1, bf1, ci * 2 + 1, acc[mi][2 + ci]);
      }
    __builtin_amdgcn_s_setprio(0);

    // ---- P2 (mh1,nh1): read af(mh1) 8; stage B1(t+1) ----
#pragma unroll
    for (int mi = 0; mi < 4; ++mi) {
      af[mi * 2 + 0] = *(const u16x8*)&Ab[wm * 8192 + 4096 + mi * 1024 + lk0];
      af[mi * 2 + 1] = *(const u16x8*)&Ab[wm * 8192 + 4096 + mi * 1024 + lk1];
    }
    stageB1(g, sbuf);
    asm volatile("s_waitcnt lgkmcnt(0)" ::: "memory");
    __builtin_amdgcn_sched_barrier(0);
    __builtin_amdgcn_s_setprio(1);
#pragma unroll
    for (int mi = 0; mi < 4; ++mi)
#pragma unroll
      for (int ci = 0; ci < 2; ++ci) {
        MFMA_Q(mi * 2 + 0, bf1, ci * 2 + 0, acc[4 + mi][2 + ci]);
        MFMA_Q(mi * 2 + 1, bf1, ci * 2 + 1, acc[4 + mi][2 + ci]);
      }
    __builtin_amdgcn_s_setprio(0);

    // ---- P3 (mh1,nh0): no reads (af + bf0 held) ----
    __builtin_amdgcn_s_setprio(1);
#pragma unroll
    for (int mi = 0; mi < 4; ++mi)
#pragma unroll
      for (int ci = 0; ci < 2; ++ci) {
        MFMA_Q(mi * 2 + 0, bf0, ci * 2 + 0, acc[4 + mi][ci]);
        MFMA_Q(mi * 2 + 1, bf0, ci * 2 + 1, acc[4 + mi][ci]);
      }
    __builtin_amdgcn_s_setprio(0);
    // no closing barrier: next tile-top vmcnt+barrier closes this tile
  }

  // epilogue: C/D layout col=lane&15, row=(lane>>4)*4+reg (R1/R3 verified)
#pragma unroll
  for (int a = 0; a < 8; ++a) {
    const int row = m0 + wm * 128 + (a >> 2) * 64 + (a & 3) * 16 + fq * 4;
#pragma unroll
    for (int b = 0; b < 4; ++b) {
      const int col = n0 + wn * 64 + (b >> 1) * 32 + (b & 1) * 16 + fr;
      const float bb = bias[col];
#pragma unroll
      for (int r = 0; r < 4; ++r)
        out[(size_t)(row + r) * OUT_F + col] = acc[a][b][r] + bb;
    }
  }
#undef MFMA_Q
}

// -------- fallback (only if ws too small): fp32 vector GEMM, LoRA fused ----
__global__ __launch_bounds__(256) void gemm_f32_fallback(
    const float* __restrict__ X, const float* __restrict__ W,
    const float* __restrict__ lA, const float* __restrict__ lB,
    const float* __restrict__ bias, float* __restrict__ out) {
  __shared__ __align__(16) float Xs[64 * 32];
  __shared__ __align__(16) float Ws[64 * 32];
  const int t = threadIdx.x;
  const int bm = blockIdx.x & 127;
  const int bn = blockIdx.x >> 7;
  const int m0 = bm * 64, n0 = bn * 64;
  const int tx = t & 15, ty = t >> 4;
  float acc[4][4] = {};
  for (int k0 = 0; k0 < IN_F; k0 += 32) {
    __syncthreads();
#pragma unroll
    for (int q = 0; q < 2; ++q) {
      const int e4 = t * 2 + q;
      const int row = e4 >> 3;
      const int col = (e4 & 7) * 4;
      float4 xv = *(const float4*)(X + (size_t)(m0 + row) * IN_F + k0 + col);
      *(float4*)(Xs + row * 32 + col) = xv;
      float4 wv = *(const float4*)(W + (size_t)(n0 + row) * IN_F + k0 + col);
#pragma unroll
      for (int r = 0; r < RANK; ++r) {
        const float a = lA[(n0 + row) * RANK + r];
        const float4 b = *(const float4*)(lB + (size_t)r * IN_F + k0 + col);
        wv.x += a * b.x; wv.y += a * b.y; wv.z += a * b.z; wv.w += a * b.w;
      }
      *(float4*)(Ws + row * 32 + col) = wv;
    }
    __syncthreads();
#pragma unroll
    for (int kk = 0; kk < 32; ++kk) {
      float xr[4], wcol[4];
#pragma unroll
      for (int i = 0; i < 4; ++i) xr[i] = Xs[(ty * 4 + i) * 32 + kk];
#pragma unroll
      for (int j = 0; j < 4; ++j) wcol[j] = Ws[(tx * 4 + j) * 32 + kk];
#pragma unroll
      for (int i = 0; i < 4; ++i)
#pragma unroll
        for (int j = 0; j < 4; ++j) acc[i][j] += xr[i] * wcol[j];
    }
  }
#pragma unroll
  for (int i = 0; i < 4; ++i) {
    const int row = m0 + ty * 4 + i;
#pragma unroll
    for (int j = 0; j < 4; ++j) {
      const int col = n0 + tx * 4 + j;
      out[(size_t)row * OUT_F + col] = acc[i][j] + bias[col];
    }
  }
}

extern "C" void kernel_launch(void* const* d_in, const int* in_sizes, int n_in,
                              void* d_out, int out_size, void* d_ws,
                              size_t ws_size, hipStream_t stream) {
  const float* x    = (const float*)d_in[0];
  const float* W    = (const float*)d_in[1];
  const float* bias = (const float*)d_in[2];
  const float* lA   = (const float*)d_in[3];
  const float* lB   = (const float*)d_in[4];
  float* out = (float*)d_out;

  const size_t MK = (size_t)MTOT * IN_F;
  const size_t NK = (size_t)OUT_F * IN_F;
  const size_t need = (MK * 2 + NK * 2) * sizeof(u16);  // 192 MiB

  if (ws_size >= need) {
    u16* Xhi = (u16*)d_ws;
    u16* Xlo = Xhi + MK;
    u16* Whi = Xlo + MK;
    u16* Wlo = Whi + NK;
    prep_kernel<<<4096, 256, 0, stream>>>(x, W, lA, lB, Xhi, Xlo, Whi, Wlo);
    gemm_pipe_kernel<<<512, 512, 0, stream>>>(Xhi, Xlo, Whi, Wlo, bias, out);
  } else {
    gemm_f32_fallback<<<128 * 64, 256, 0, stream>>>(x, W, lA, lB, bias, out);
  }
}

// Round 7
// 883.262 us; speedup vs baseline: 1.4468x; 1.0310x over previous
//
#include <hip/hip_runtime.h>
#include <hip/hip_bf16.h>
#include <stdint.h>

// LoRALinear fused: y = x @ (W + lora_A @ lora_B)^T + bias
// W_eff = W + A@B folded; x, W_eff split to bf16 hi+lo; 3-segment bf16 MFMA
// GEMM (hi*hi + lo*hi + hi*lo), fp32 accumulate. K_eff = 3*4096 = 12288.
// R7 GEMM = R6 skeleton (BK=64 dbuf, 1 barrier + 1 vmcnt(0)/tile, XOR swizzle,
// setprio) + front-loaded ds_read issue with COMPILER-counted lgkmcnt waits
// (hand lgkmcnt(0) removed; sched_barrier(0) pins phase boundaries only),
// af2 regs for mh1 so its reads overlap P1's MFMAs, P2+P3 merged (32 MFMA).
// R7 prep: W-half keeps its 16 lB values in registers (kills 16x L2 re-read).

typedef unsigned short u16;
typedef __attribute__((ext_vector_type(8))) u16 u16x8;
typedef __attribute__((ext_vector_type(4))) u16 u16x4;
typedef __attribute__((ext_vector_type(8))) __bf16 bf16x8;
typedef __attribute__((ext_vector_type(4))) float f32x4;

#define IN_F 4096
#define OUT_F 4096
#define MTOT 8192  // B*S
#define RANK 16
#define NT64 192  // 3 segments * (4096/64) K-tiles

__device__ __forceinline__ u16 f2bf(float f) {
  unsigned u = __float_as_uint(f);
  unsigned r = u + 0x7FFFu + ((u >> 16) & 1u);
  return (u16)(r >> 16);
}
__device__ __forceinline__ float bf2f(u16 h) {
  return __uint_as_float(((unsigned)h) << 16);
}

// ---------------- fused prep ----------------
// blocks [0,3072): x -> Xhi,Xlo (grid-stride).
// blocks [3072,4096): W_eff -> Whi,Wlo. 1024 blocks = 32 k-strips x 32
// o-groups; thread owns ONE k-column (i4), preloads lB[0..15][i4] into regs,
// streams 16 o-rows. lB L2 traffic: 1.07 GB -> 67 MB.
__global__ __launch_bounds__(256) void prep_kernel(
    const float* __restrict__ x, const float* __restrict__ W,
    const float* __restrict__ lA, const float* __restrict__ lB,
    u16* __restrict__ xhi, u16* __restrict__ xlo, u16* __restrict__ whi,
    u16* __restrict__ wlo) {
  const int t = threadIdx.x;
  if (blockIdx.x < 3072) {
    const int n4 = (MTOT * IN_F) / 4;
    int idx = blockIdx.x * 256 + t;
    for (; idx < n4; idx += 3072 * 256) {
      float4 v = ((const float4*)x)[idx];
      u16x4 h, l;
      h.x = f2bf(v.x); l.x = f2bf(v.x - bf2f(h.x));
      h.y = f2bf(v.y); l.y = f2bf(v.y - bf2f(h.y));
      h.z = f2bf(v.z); l.z = f2bf(v.z - bf2f(h.z));
      h.w = f2bf(v.w); l.w = f2bf(v.w - bf2f(h.w));
      ((u16x4*)xhi)[idx] = h;
      ((u16x4*)xlo)[idx] = l;
    }
  } else {
    const int bw = blockIdx.x - 3072;
    const int strip = bw & 31;   // k-strip (32 x 128 elems)
    const int og = bw >> 5;      // o-group (32 x 128 rows)
    const int i4 = strip * 32 + (t & 31);  // this thread's float4 column
    float4 lbr[RANK];
#pragma unroll
    for (int r = 0; r < RANK; ++r)
      lbr[r] = ((const float4*)lB)[r * (IN_F / 4) + i4];
#pragma unroll 1
    for (int j = 0; j < 16; ++j) {
      const int o = og * 128 + (t >> 5) + 8 * j;
      float a[RANK];
#pragma unroll
      for (int q = 0; q < 4; ++q) {
        float4 av = ((const float4*)lA)[o * (RANK / 4) + q];
        a[q * 4 + 0] = av.x; a[q * 4 + 1] = av.y;
        a[q * 4 + 2] = av.z; a[q * 4 + 3] = av.w;
      }
      float4 acc = ((const float4*)W)[o * (IN_F / 4) + i4];
#pragma unroll
      for (int r = 0; r < RANK; ++r) {
        acc.x += a[r] * lbr[r].x; acc.y += a[r] * lbr[r].y;
        acc.z += a[r] * lbr[r].z; acc.w += a[r] * lbr[r].w;
      }
      u16x4 h, l;
      h.x = f2bf(acc.x); l.x = f2bf(acc.x - bf2f(h.x));
      h.y = f2bf(acc.y); l.y = f2bf(acc.y - bf2f(h.y));
      h.z = f2bf(acc.z); l.z = f2bf(acc.z - bf2f(h.z));
      h.w = f2bf(acc.w); l.w = f2bf(acc.w - bf2f(h.w));
      ((u16x4*)whi)[o * (IN_F / 4) + i4] = h;
      ((u16x4*)wlo)[o * (IN_F / 4) + i4] = l;
    }
  }
}

// ---------------- main: BK=64 front-loaded-issue 3-segment bf16 GEMM -------
#define GLD_LDS16(g, l)                                                  \
  __builtin_amdgcn_global_load_lds(                                      \
      (const __attribute__((address_space(1))) void*)(g),                \
      (__attribute__((address_space(3))) void*)(l), 16, 0, 0)

__global__ __launch_bounds__(512, 2) void gemm_pipe_kernel(
    const u16* __restrict__ Xhi, const u16* __restrict__ Xlo,
    const u16* __restrict__ Whi, const u16* __restrict__ Wlo,
    const float* __restrict__ bias, float* __restrict__ out) {
  // 2 bufs x (A 256x64 | B 256x64) bf16 = 2 x 64 KiB = 128 KiB.
  // unit = 16B chunk. Row r slot s: unit = r*8+s; global chunk c of row r
  // lands at slot s = c ^ (r&7)  (conflict-free ds_read_b128; 0 in R3/R6).
  __shared__ __align__(16) u16 LDS[65536];

  const int t = threadIdx.x;
  const int lane = t & 63;
  const int wv = t >> 6;   // 0..7
  const int wm = wv >> 2;  // 0..1: 128-row half
  const int wn = wv & 3;   // 0..3: 64-col strip
  const int fr = lane & 15;
  const int fq = lane >> 4;

  // T1: XCD swizzle (bijective: 512 % 8 == 0), 64 contiguous wgs per XCD.
  const int wg = ((blockIdx.x & 7) << 6) | (blockIdx.x >> 3);
  const int m0 = (wg >> 4) * 256;  // 32 m-tiles
  const int n0 = (wg & 15) * 256;  // 16 n-tiles

  // staging source: thread t stages dst unit (h*1024+q*512+t) <- global row
  // (h&1)*128 + q*64 + (t>>3), chunk (t&7)^((t>>3)&7).
  const int scol = ((t & 7) ^ ((t >> 3) & 7)) * 8;
  const size_t aoff = (size_t)(m0 + (t >> 3)) * IN_F + scol;
  const size_t boff = (size_t)(n0 + (t >> 3)) * IN_F + scol;

  // ds_read lane offsets (u16): frag(row base R, kstep ks) at
  // (R+fr)*64 + ((ks*4+fq)^(fr&7))*8   (R%8==0 everywhere)
  const int lk0 = fr * 64 + (((0 * 4 + fq) ^ (fr & 7)) * 8);
  const int lk1 = fr * 64 + (((1 * 4 + fq) ^ (fr & 7)) * 8);

  f32x4 acc[8][4];  // [mh*4+mi][nh*2+ci]
#pragma unroll
  for (int i = 0; i < 8; ++i)
#pragma unroll
    for (int j = 0; j < 4; ++j) {
      acc[i][j][0] = 0.f; acc[i][j][1] = 0.f;
      acc[i][j][2] = 0.f; acc[i][j][3] = 0.f;
    }

  // segment g>>6: A from {Xhi,Xlo,Xhi}; B from {Whi,Whi,Wlo}
  auto stageA = [&](int g, int sbuf) {  // 4 gld
    const int sg = g >> 6;
    const u16* ap = (sg == 1) ? Xlo : Xhi;
    const int k0 = (g & 63) << 6;
    u16* dA = (u16*)&LDS[sbuf * 32768];
    const u16* s = ap + aoff + k0;
    GLD_LDS16(s, dA + t * 8);
    GLD_LDS16(s + (size_t)64 * IN_F, dA + (512 + t) * 8);
    GLD_LDS16(s + (size_t)128 * IN_F, dA + (1024 + t) * 8);
    GLD_LDS16(s + (size_t)192 * IN_F, dA + (1536 + t) * 8);
  };
  auto stageB = [&](int g, int sbuf) {  // 4 gld
    const int sg = g >> 6;
    const u16* bp = (sg == 2) ? Wlo : Whi;
    const int k0 = (g & 63) << 6;
    u16* dB = (u16*)&LDS[sbuf * 32768 + 16384];
    const u16* s = bp + boff + k0;
    GLD_LDS16(s, dB + t * 8);
    GLD_LDS16(s + (size_t)64 * IN_F, dB + (512 + t) * 8);
    GLD_LDS16(s + (size_t)128 * IN_F, dB + (1024 + t) * 8);
    GLD_LDS16(s + (size_t)192 * IN_F, dB + (1536 + t) * 8);
  };

#define MFMA_Q(AARR, AIDX, BARR, BIDX, ACC)                             \
  ACC = __builtin_amdgcn_mfma_f32_16x16x32_bf16(                        \
      __builtin_bit_cast(bf16x8, AARR[AIDX]),                           \
      __builtin_bit_cast(bf16x8, BARR[BIDX]), ACC, 0, 0, 0)

  // prologue: stage tile 0 into buf 0 (8 loads)
  stageA(0, 0); stageB(0, 0);

#pragma unroll 1
  for (int tt = 0; tt < NT64; ++tt) {
    const int buf = tt & 1;
    const u16* Ab = &LDS[buf * 32768];
    const u16* Bb = Ab + 16384;
    int g = tt + 1;
    if (g >= NT64) g = NT64 - 1;  // dummy re-stage: uniform vmcnt ledger
    const int sbuf = buf ^ 1;

    // next-tile loads were issued >=2 phases (~2000 cy) ago: drain ~free.
    // barrier => all waves' tile-tt loads landed; all sbuf readers done
    // (each wave's ds_reads completed before its P2P3 MFMAs last tile).
    asm volatile("s_waitcnt vmcnt(0)" ::: "memory");
    __builtin_amdgcn_s_barrier();
    __builtin_amdgcn_sched_barrier(0);  // nothing hoists above the barrier

    u16x8 af[8], af2[8], bf0[4], bf1[4];

    // ---- region 0: issue af(mh0) 8 + bf0 4 + bf1 4; stage A(t+1) ----
#pragma unroll
    for (int mi = 0; mi < 4; ++mi) {
      af[mi * 2 + 0] = *(const u16x8*)&Ab[wm * 8192 + mi * 1024 + lk0];
      af[mi * 2 + 1] = *(const u16x8*)&Ab[wm * 8192 + mi * 1024 + lk1];
    }
#pragma unroll
    for (int ci = 0; ci < 2; ++ci) {
      bf0[ci * 2 + 0] = *(const u16x8*)&Bb[wn * 4096 + ci * 1024 + lk0];
      bf0[ci * 2 + 1] = *(const u16x8*)&Bb[wn * 4096 + ci * 1024 + lk1];
      bf1[ci * 2 + 0] = *(const u16x8*)&Bb[wn * 4096 + 2048 + ci * 1024 + lk0];
      bf1[ci * 2 + 1] = *(const u16x8*)&Bb[wn * 4096 + 2048 + ci * 1024 + lk1];
    }
    stageA(g, sbuf);
    __builtin_amdgcn_sched_barrier(0);

    // ---- P0 (mh0 x nh0): compiler inserts exact counted lgkmcnt ----
    __builtin_amdgcn_s_setprio(1);
#pragma unroll
    for (int mi = 0; mi < 4; ++mi)
#pragma unroll
      for (int ci = 0; ci < 2; ++ci) {
        MFMA_Q(af, mi * 2 + 0, bf0, ci * 2 + 0, acc[mi][ci]);
        MFMA_Q(af, mi * 2 + 1, bf0, ci * 2 + 1, acc[mi][ci]);
      }
    __builtin_amdgcn_s_setprio(0);
    __builtin_amdgcn_sched_barrier(0);

    // ---- region 1: issue af2(mh1) 8 (overlaps P1); stage B(t+1) ----
#pragma unroll
    for (int mi = 0; mi < 4; ++mi) {
      af2[mi * 2 + 0] = *(const u16x8*)&Ab[wm * 8192 + 4096 + mi * 1024 + lk0];
      af2[mi * 2 + 1] = *(const u16x8*)&Ab[wm * 8192 + 4096 + mi * 1024 + lk1];
    }
    stageB(g, sbuf);
    __builtin_amdgcn_sched_barrier(0);

    // ---- P1 (mh0 x nh1): bf1 was issued one phase ago -> wait ~free ----
    __builtin_amdgcn_s_setprio(1);
#pragma unroll
    for (int mi = 0; mi < 4; ++mi)
#pragma unroll
      for (int ci = 0; ci < 2; ++ci) {
        MFMA_Q(af, mi * 2 + 0, bf1, ci * 2 + 0, acc[mi][2 + ci]);
        MFMA_Q(af, mi * 2 + 1, bf1, ci * 2 + 1, acc[mi][2 + ci]);
      }
    __builtin_amdgcn_s_setprio(0);
    __builtin_amdgcn_sched_barrier(0);

    // ---- P2+P3 (mh1 x nh1, mh1 x nh0): af2 overlapped with P1 ----
    __builtin_amdgcn_s_setprio(1);
#pragma unroll
    for (int mi = 0; mi < 4; ++mi)
#pragma unroll
      for (int ci = 0; ci < 2; ++ci) {
        MFMA_Q(af2, mi * 2 + 0, bf1, ci * 2 + 0, acc[4 + mi][2 + ci]);
        MFMA_Q(af2, mi * 2 + 1, bf1, ci * 2 + 1, acc[4 + mi][2 + ci]);
      }
#pragma unroll
    for (int mi = 0; mi < 4; ++mi)
#pragma unroll
      for (int ci = 0; ci < 2; ++ci) {
        MFMA_Q(af2, mi * 2 + 0, bf0, ci * 2 + 0, acc[4 + mi][ci]);
        MFMA_Q(af2, mi * 2 + 1, bf0, ci * 2 + 1, acc[4 + mi][ci]);
      }
    __builtin_amdgcn_s_setprio(0);
    // no closing barrier: next tile-top vmcnt+barrier closes this tile
  }

  // epilogue: C/D layout col=lane&15, row=(lane>>4)*4+reg (R1/R3/R6 verified)
#pragma unroll
  for (int a = 0; a < 8; ++a) {
    const int row = m0 + wm * 128 + (a >> 2) * 64 + (a & 3) * 16 + fq * 4;
#pragma unroll
    for (int b = 0; b < 4; ++b) {
      const int col = n0 + wn * 64 + (b >> 1) * 32 + (b & 1) * 16 + fr;
      const float bb = bias[col];
#pragma unroll
      for (int r = 0; r < 4; ++r)
        out[(size_t)(row + r) * OUT_F + col] = acc[a][b][r] + bb;
    }
  }
#undef MFMA_Q
}

// -------- fallback (only if ws too small): fp32 vector GEMM, LoRA fused ----
__global__ __launch_bounds__(256) void gemm_f32_fallback(
    const float* __restrict__ X, const float* __restrict__ W,
    const float* __restrict__ lA, const float* __restrict__ lB,
    const float* __restrict__ bias, float* __restrict__ out) {
  __shared__ __align__(16) float Xs[64 * 32];
  __shared__ __align__(16) float Ws[64 * 32];
  const int t = threadIdx.x;
  const int bm = blockIdx.x & 127;
  const int bn = blockIdx.x >> 7;
  const int m0 = bm * 64, n0 = bn * 64;
  const int tx = t & 15, ty = t >> 4;
  float acc[4][4] = {};
  for (int k0 = 0; k0 < IN_F; k0 += 32) {
    __syncthreads();
#pragma unroll
    for (int q = 0; q < 2; ++q) {
      const int e4 = t * 2 + q;
      const int row = e4 >> 3;
      const int col = (e4 & 7) * 4;
      float4 xv = *(const float4*)(X + (size_t)(m0 + row) * IN_F + k0 + col);
      *(float4*)(Xs + row * 32 + col) = xv;
      float4 wv = *(const float4*)(W + (size_t)(n0 + row) * IN_F + k0 + col);
#pragma unroll
      for (int r = 0; r < RANK; ++r) {
        const float a = lA[(n0 + row) * RANK + r];
        const float4 b = *(const float4*)(lB + (size_t)r * IN_F + k0 + col);
        wv.x += a * b.x; wv.y += a * b.y; wv.z += a * b.z; wv.w += a * b.w;
      }
      *(float4*)(Ws + row * 32 + col) = wv;
    }
    __syncthreads();
#pragma unroll
    for (int kk = 0; kk < 32; ++kk) {
      float xr[4], wcol[4];
#pragma unroll
      for (int i = 0; i < 4; ++i) xr[i] = Xs[(ty * 4 + i) * 32 + kk];
#pragma unroll
      for (int j = 0; j < 4; ++j) wcol[j] = Ws[(tx * 4 + j) * 32 + kk];
#pragma unroll
      for (int i = 0; i < 4; ++i)
#pragma unroll
        for (int j = 0; j < 4; ++j) acc[i][j] += xr[i] * wcol[j];
    }
  }
#pragma unroll
  for (int i = 0; i < 4; ++i) {
    const int row = m0 + ty * 4 + i;
#pragma unroll
    for (int j = 0; j < 4; ++j) {
      const int col = n0 + tx * 4 + j;
      out[(size_t)row * OUT_F + col] = acc[i][j] + bias[col];
    }
  }
}

extern "C" void kernel_launch(void* const* d_in, const int* in_sizes, int n_in,
                              void* d_out, int out_size, void* d_ws,
                              size_t ws_size, hipStream_t stream) {
  const float* x    = (const float*)d_in[0];
  const float* W    = (const float*)d_in[1];
  const float* bias = (const float*)d_in[2];
  const float* lA   = (const float*)d_in[3];
  const float* lB   = (const float*)d_in[4];
  float* out = (float*)d_out;

  const size_t MK = (size_t)MTOT * IN_F;
  const size_t NK = (size_t)OUT_F * IN_F;
  const size_t need = (MK * 2 + NK * 2) * sizeof(u16);  // 192 MiB

  if (ws_size >= need) {
    u16* Xhi = (u16*)d_ws;
    u16* Xlo = Xhi + MK;
    u16* Whi = Xlo + MK;
    u16* Wlo = Whi + NK;
    prep_kernel<<<4096, 256, 0, stream>>>(x, W, lA, lB, Xhi, Xlo, Whi, Wlo);
    gemm_pipe_kernel<<<512, 512, 0, stream>>>(Xhi, Xlo, Whi, Wlo, bias, out);
  } else {
    gemm_f32_fallback<<<128 * 64, 256, 0, stream>>>(x, W, lA, lB, bias, out);
  }
}